// Round 2
// baseline (76.222 us; speedup 1.0000x reference)
//
#include <hip/hip_runtime.h>

#define NB 512          // batch
#define FD 512          // feat dims
#define GRP 8           // group size
#define KSPLIT 4
#define KCH (FD / KSPLIT)   // 128 k per block
#define KSUB 64             // staged k sub-chunk
#define TM 64
#define TN 64

// ---------------------------------------------------------------------------
// K1: fp32 GEMM  sim = f_s @ f_t^T, split-K into KSPLIT partial slices in ws.
// grid = (NB/TM)*(NB/TN)*KSPLIT = 8*8*4 = 256 blocks, 256 threads.
// Each thread: 4x4 register tile; LDS fragments are float4-over-k with
// XOR-swizzled slots (slot = s ^ (row>>2)) -> 2-way conflicts max (free).
// Global->register double buffering: chunk kc+1's loads are issued before
// chunk kc's inner product, hiding the global-load latency.
// ---------------------------------------------------------------------------
__global__ __launch_bounds__(256)
void k_gemm(const float* __restrict__ fs, const float* __restrict__ ft,
            float* __restrict__ simsl, float* __restrict__ out1)
{
    __shared__ float4 Asv[TM * (KSUB / 4)];   // [64][16] float4 slots
    __shared__ float4 Bsv[TN * (KSUB / 4)];

    const int tid  = threadIdx.x;
    const int bid  = blockIdx.x;
    const int ks   = bid >> 6;        // k-slice 0..3
    const int tile = bid & 63;
    const int tr   = (tile >> 3) * TM;
    const int tc   = (tile & 7) * TN;
    const int ty   = tid >> 4;        // 0..15
    const int tx   = tid & 15;        // 0..15

    if (bid == 0 && tid == 0) out1[0] = 1.0f;   // K2 accumulates -ap into this

    float acc[4][4];
    #pragma unroll
    for (int i = 0; i < 4; ++i)
        #pragma unroll
        for (int j = 0; j < 4; ++j) acc[i][j] = 0.f;

    // staging addresses for this thread (4 A rows + 4 B rows per chunk)
    const int k0 = ks * KCH;
    int srow[4], sslot[4];
    #pragma unroll
    for (int u = 0; u < 4; ++u) {
        const int idx = tid + 256 * u;     // 0..1023
        srow[u]  = idx >> 4;               // 0..63
        sslot[u] = idx & 15;               // float4 slot within row
    }

    float4 abuf[4], bbuf[4];
    // prologue: load chunk 0 into registers
    #pragma unroll
    for (int u = 0; u < 4; ++u) {
        abuf[u] = *(const float4*)(fs + (size_t)(tr + srow[u]) * FD + k0 + 4 * sslot[u]);
        bbuf[u] = *(const float4*)(ft + (size_t)(tc + srow[u]) * FD + k0 + 4 * sslot[u]);
    }

    for (int kc = 0; kc < KCH; kc += KSUB) {
        // write current chunk regs -> LDS (XOR swizzle)
        #pragma unroll
        for (int u = 0; u < 4; ++u) {
            const int slot = sslot[u] ^ (srow[u] >> 2);
            Asv[srow[u] * 16 + slot] = abuf[u];
            Bsv[srow[u] * 16 + slot] = bbuf[u];
        }
        __syncthreads();

        // issue next chunk's global loads (overlap with inner product)
        if (kc + KSUB < KCH) {
            const int kk = k0 + kc + KSUB;
            #pragma unroll
            for (int u = 0; u < 4; ++u) {
                abuf[u] = *(const float4*)(fs + (size_t)(tr + srow[u]) * FD + kk + 4 * sslot[u]);
                bbuf[u] = *(const float4*)(ft + (size_t)(tc + srow[u]) * FD + kk + 4 * sslot[u]);
            }
        }

        #pragma unroll
        for (int s = 0; s < KSUB / 4; ++s) {
            float4 a[4], b[4];
            #pragma unroll
            for (int i = 0; i < 4; ++i)
                a[i] = Asv[(4 * ty + i) * 16 + (s ^ ty)];   // (4ty+i)>>2 == ty
            #pragma unroll
            for (int j = 0; j < 4; ++j)
                b[j] = Bsv[(4 * tx + j) * 16 + (s ^ tx)];
            #pragma unroll
            for (int i = 0; i < 4; ++i)
                #pragma unroll
                for (int j = 0; j < 4; ++j) {
                    acc[i][j] = fmaf(a[i].x, b[j].x, acc[i][j]);
                    acc[i][j] = fmaf(a[i].y, b[j].y, acc[i][j]);
                    acc[i][j] = fmaf(a[i].z, b[j].z, acc[i][j]);
                    acc[i][j] = fmaf(a[i].w, b[j].w, acc[i][j]);
                }
        }
        __syncthreads();
    }

    float* dst = simsl + (size_t)ks * NB * NB;
    #pragma unroll
    for (int i = 0; i < 4; ++i) {
        float4 v = make_float4(acc[i][0], acc[i][1], acc[i][2], acc[i][3]);
        *(float4*)(dst + (size_t)(tr + 4 * ty + i) * NB + tc + 4 * tx) = v;
    }
}

// ---------------------------------------------------------------------------
// K2: per-row rank reduction + SmoothAP contribution.
// 512 blocks (one per row b) x 64 threads (one wave).
// Lane l owns columns j = 8l..8l+7.  rank_all[q] = 1 + sum_j relu(r[j]-s[q]);
// rank_pos[q] = 1 + sum_k relu(s[k]-s[q]);  contrib = sum_q rp[q]/ra[q].
// out1 starts at 1.0 (written by K1); blocks atomicAdd(-contrib/4096).
// ---------------------------------------------------------------------------
__global__ __launch_bounds__(64)
void k_rank(const float* __restrict__ simsl, float* __restrict__ out1)
{
    const int b = blockIdx.x;
    const int l = threadIdx.x;
    const int n = b >> 3;           // identity group of this row

    float r[8];
    #pragma unroll
    for (int q = 0; q < 8; ++q) r[q] = 0.f;
    #pragma unroll
    for (int ks = 0; ks < KSPLIT; ++ks) {
        const float* p = simsl + (size_t)ks * NB * NB + (size_t)b * NB + 8 * l;
        float4 u = *(const float4*)(p);
        float4 v = *(const float4*)(p + 4);
        r[0] += u.x; r[1] += u.y; r[2] += u.z; r[3] += u.w;
        r[4] += v.x; r[5] += v.y; r[6] += v.z; r[7] += v.w;
    }

    // s[q] = sim[b, 8n+q] : lane n holds exactly those 8 values in r[0..7]
    float s[8];
    #pragma unroll
    for (int q = 0; q < 8; ++q) s[q] = __shfl(r[q], n);

    // per-lane partial rank_all sums over this lane's 8 columns
    float a[8];
    #pragma unroll
    for (int q = 0; q < 8; ++q) a[q] = 0.f;
    #pragma unroll
    for (int q = 0; q < 8; ++q)
        #pragma unroll
        for (int jj = 0; jj < 8; ++jj)
            a[q] += fmaxf(r[jj] - s[q], 0.f);

    // 64-lane butterfly reduce (all lanes end with the full sums)
    #pragma unroll
    for (int off = 1; off < 64; off <<= 1)
        #pragma unroll
        for (int q = 0; q < 8; ++q)
            a[q] += __shfl_xor(a[q], off);

    float contrib = 0.f;
    if (l < 8) {
        float rp = 1.f;
        #pragma unroll
        for (int k = 0; k < 8; ++k) rp += fmaxf(s[k] - s[l], 0.f);
        contrib = rp / (1.f + a[l]);
    }
    contrib += __shfl_xor(contrib, 1);
    contrib += __shfl_xor(contrib, 2);
    contrib += __shfl_xor(contrib, 4);
    if (l == 0) atomicAdd(out1, -contrib * (1.f / (GRP * NB)));
}

// ---------------------------------------------------------------------------
extern "C" void kernel_launch(void* const* d_in, const int* in_sizes, int n_in,
                              void* d_out, int out_size, void* d_ws, size_t ws_size,
                              hipStream_t stream)
{
    const float* fs = (const float*)d_in[0];   // f_s (512x512 f32)
    const float* ft = (const float*)d_in[1];   // f_t (512x512 f32)
    float* out   = (float*)d_out;              // scalar f32
    float* simsl = (float*)d_ws;               // KSPLIT * 512*512 f32 = 4 MB

    k_gemm<<<dim3(256), dim3(256), 0, stream>>>(fs, ft, simsl, out);
    k_rank<<<dim3(512), dim3(64), 0, stream>>>(simsl, out);
}

// Round 3
// 70.237 us; speedup vs baseline: 1.0852x; 1.0852x over previous
//
#include <hip/hip_runtime.h>

typedef __attribute__((ext_vector_type(8))) short bf16x8;
typedef __attribute__((ext_vector_type(4))) float f32x4;

#define NB 512
#define FD 512
#define PLANE (NB * FD)          // 262144 elements per plane

// fp32 -> bf16 round-to-nearest-even (bit twiddle; inputs are finite normals)
__device__ __forceinline__ ushort f2bf(float x) {
    uint u = __builtin_bit_cast(uint, x);
    return (ushort)((u + 0x7FFFu + ((u >> 16) & 1u)) >> 16);
}
__device__ __forceinline__ float bf2f(ushort h) {
    uint u = ((uint)h) << 16;
    return __builtin_bit_cast(float, u);
}

// ---------------------------------------------------------------------------
// k_split: fp32 inputs -> 4 bf16 planes in ws: fs_hi | fs_lo | ft_hi | ft_lo.
// 3-term split GEMM (hi*hi + hi*lo + lo*hi) recovers ~fp32 accuracy.
// 512 blocks x 256 threads, one float4 per thread. Also seeds out[0] = 1.0.
// ---------------------------------------------------------------------------
__global__ __launch_bounds__(256)
void k_split(const float* __restrict__ fs, const float* __restrict__ ft,
             ushort* __restrict__ planes, float* __restrict__ out1)
{
    const int t = blockIdx.x * 256 + threadIdx.x;   // 0..131071 float4 chunks
    if (t == 0) out1[0] = 1.0f;                     // k_rank accumulates -ap
    const int mat = t >> 16;                        // 0 = fs, 1 = ft
    const int i4  = t & 65535;                      // float4 index within matrix
    const float4 v = ((const float4*)(mat ? ft : fs))[i4];

    ushort4 hi, lo;
    hi.x = f2bf(v.x); lo.x = f2bf(v.x - bf2f(hi.x));
    hi.y = f2bf(v.y); lo.y = f2bf(v.y - bf2f(hi.y));
    hi.z = f2bf(v.z); lo.z = f2bf(v.z - bf2f(hi.z));
    hi.w = f2bf(v.w); lo.w = f2bf(v.w - bf2f(hi.w));

    ushort4* hp = (ushort4*)(planes + (size_t)mat * 2 * PLANE);
    ushort4* lp = (ushort4*)(planes + (size_t)mat * 2 * PLANE + PLANE);
    hp[i4] = hi;
    lp[i4] = lo;
}

// ---------------------------------------------------------------------------
// k_mm: sim = fs @ ft^T via mfma_f32_16x16x32_bf16, 3-term hi/lo split.
// 256 blocks x 64 threads (1 wave): each wave owns a 32x32 tile, NO LDS —
// fragments load directly from the bf16 planes (16B dwordx4, L2-hot).
// Frag layout (verified m89/m91): A/B lane l = row (l&15), k = 8*(l>>4)+i;
// C/D: col = l&15, row = (l>>4)*4 + reg.
// ---------------------------------------------------------------------------
__global__ __launch_bounds__(64)
void k_mm(const ushort* __restrict__ planes, float* __restrict__ sim)
{
    const int l   = threadIdx.x;
    const int bid = blockIdx.x;              // 16 x 16 tiles of 32x32
    const int tr  = (bid >> 4) * 32;
    const int tc  = (bid & 15) * 32;
    const int r0  = l & 15;
    const int kg  = (l >> 4) * 8;            // this lane's k sub-offset

    const ushort* fsh = planes;
    const ushort* fsl = planes + PLANE;
    const ushort* fth = planes + 2 * PLANE;
    const ushort* ftl = planes + 3 * PLANE;

    // 8 per-lane row base pointers (2 m-halves x hi/lo, 2 n-halves x hi/lo)
    const ushort* pa0h = fsh + (size_t)(tr + r0)      * FD + kg;
    const ushort* pa1h = fsh + (size_t)(tr + r0 + 16) * FD + kg;
    const ushort* pa0l = fsl + (size_t)(tr + r0)      * FD + kg;
    const ushort* pa1l = fsl + (size_t)(tr + r0 + 16) * FD + kg;
    const ushort* pb0h = fth + (size_t)(tc + r0)      * FD + kg;
    const ushort* pb1h = fth + (size_t)(tc + r0 + 16) * FD + kg;
    const ushort* pb0l = ftl + (size_t)(tc + r0)      * FD + kg;
    const ushort* pb1l = ftl + (size_t)(tc + r0 + 16) * FD + kg;

    f32x4 acc[2][2];
    #pragma unroll
    for (int i = 0; i < 2; ++i)
        #pragma unroll
        for (int j = 0; j < 2; ++j) acc[i][j] = (f32x4){0.f, 0.f, 0.f, 0.f};

    #pragma unroll 4
    for (int k = 0; k < FD; k += 32) {
        const bf16x8 a0h = *(const bf16x8*)(pa0h + k);
        const bf16x8 a1h = *(const bf16x8*)(pa1h + k);
        const bf16x8 a0l = *(const bf16x8*)(pa0l + k);
        const bf16x8 a1l = *(const bf16x8*)(pa1l + k);
        const bf16x8 b0h = *(const bf16x8*)(pb0h + k);
        const bf16x8 b1h = *(const bf16x8*)(pb1h + k);
        const bf16x8 b0l = *(const bf16x8*)(pb0l + k);
        const bf16x8 b1l = *(const bf16x8*)(pb1l + k);

        acc[0][0] = __builtin_amdgcn_mfma_f32_16x16x32_bf16(a0h, b0h, acc[0][0], 0, 0, 0);
        acc[0][0] = __builtin_amdgcn_mfma_f32_16x16x32_bf16(a0h, b0l, acc[0][0], 0, 0, 0);
        acc[0][0] = __builtin_amdgcn_mfma_f32_16x16x32_bf16(a0l, b0h, acc[0][0], 0, 0, 0);
        acc[0][1] = __builtin_amdgcn_mfma_f32_16x16x32_bf16(a0h, b1h, acc[0][1], 0, 0, 0);
        acc[0][1] = __builtin_amdgcn_mfma_f32_16x16x32_bf16(a0h, b1l, acc[0][1], 0, 0, 0);
        acc[0][1] = __builtin_amdgcn_mfma_f32_16x16x32_bf16(a0l, b1h, acc[0][1], 0, 0, 0);
        acc[1][0] = __builtin_amdgcn_mfma_f32_16x16x32_bf16(a1h, b0h, acc[1][0], 0, 0, 0);
        acc[1][0] = __builtin_amdgcn_mfma_f32_16x16x32_bf16(a1h, b0l, acc[1][0], 0, 0, 0);
        acc[1][0] = __builtin_amdgcn_mfma_f32_16x16x32_bf16(a1l, b0h, acc[1][0], 0, 0, 0);
        acc[1][1] = __builtin_amdgcn_mfma_f32_16x16x32_bf16(a1h, b1h, acc[1][1], 0, 0, 0);
        acc[1][1] = __builtin_amdgcn_mfma_f32_16x16x32_bf16(a1h, b1l, acc[1][1], 0, 0, 0);
        acc[1][1] = __builtin_amdgcn_mfma_f32_16x16x32_bf16(a1l, b1h, acc[1][1], 0, 0, 0);
    }

    // store: row = tr + mh*16 + (l>>4)*4 + j, col = tc + nh*16 + r0
    const int rbase = (l >> 4) * 4;
    #pragma unroll
    for (int mh = 0; mh < 2; ++mh)
        #pragma unroll
        for (int j = 0; j < 4; ++j) {
            const int row = tr + mh * 16 + rbase + j;
            sim[(size_t)row * NB + tc + r0]      = acc[mh][0][j];
            sim[(size_t)row * NB + tc + 16 + r0] = acc[mh][1][j];
        }
}

// ---------------------------------------------------------------------------
// k_rank: per-row rank reduction + SmoothAP contribution.
// 64 blocks (one per identity group) x 512 threads (8 waves, one row each).
// Lane l owns columns 8l..8l+7; lane n==blockIdx holds the in-group sims.
// Block-reduces 8 wave contribs in LDS -> ONE atomic per block (64 total).
// ---------------------------------------------------------------------------
__global__ __launch_bounds__(512)
void k_rank(const float* __restrict__ sim, float* __restrict__ out1)
{
    __shared__ float part[8];
    const int w = threadIdx.x >> 6;     // wave 0..7 -> row within group
    const int l = threadIdx.x & 63;
    const int n = blockIdx.x;           // identity group (= b>>3)
    const int b = n * 8 + w;

    const float* p = sim + (size_t)b * NB + 8 * l;
    const float4 u = *(const float4*)(p);
    const float4 v = *(const float4*)(p + 4);
    float r[8] = {u.x, u.y, u.z, u.w, v.x, v.y, v.z, v.w};

    // s[q] = sim[b, 8n+q]: lane n holds exactly those 8 values
    float s[8];
    #pragma unroll
    for (int q = 0; q < 8; ++q) s[q] = __shfl(r[q], n);

    // per-lane partial rank_all sums over this lane's 8 columns
    float a[8];
    #pragma unroll
    for (int q = 0; q < 8; ++q) a[q] = 0.f;
    #pragma unroll
    for (int q = 0; q < 8; ++q)
        #pragma unroll
        for (int jj = 0; jj < 8; ++jj)
            a[q] += fmaxf(r[jj] - s[q], 0.f);

    // 64-lane butterfly reduce
    #pragma unroll
    for (int off = 1; off < 64; off <<= 1)
        #pragma unroll
        for (int q = 0; q < 8; ++q)
            a[q] += __shfl_xor(a[q], off);

    float contrib = 0.f;
    if (l < 8) {
        float rp = 1.f;
        #pragma unroll
        for (int k = 0; k < 8; ++k) rp += fmaxf(s[k] - s[l], 0.f);
        contrib = rp / (1.f + a[l]);
    }
    contrib += __shfl_xor(contrib, 1);
    contrib += __shfl_xor(contrib, 2);
    contrib += __shfl_xor(contrib, 4);
    if (l == 0) part[w] = contrib;
    __syncthreads();

    if (threadIdx.x == 0) {
        float t = 0.f;
        #pragma unroll
        for (int i = 0; i < 8; ++i) t += part[i];
        atomicAdd(out1, -t * (1.f / (8.f * NB)));
    }
}

// ---------------------------------------------------------------------------
extern "C" void kernel_launch(void* const* d_in, const int* in_sizes, int n_in,
                              void* d_out, int out_size, void* d_ws, size_t ws_size,
                              hipStream_t stream)
{
    const float* fs = (const float*)d_in[0];   // f_s (512x512 f32)
    const float* ft = (const float*)d_in[1];   // f_t (512x512 f32)
    float* out = (float*)d_out;                // scalar f32

    ushort* planes = (ushort*)d_ws;                          // 4 bf16 planes, 2 MB
    float*  sim    = (float*)((char*)d_ws + 4ull * PLANE * sizeof(ushort)); // 1 MB

    k_split<<<dim3(512), dim3(256), 0, stream>>>(fs, ft, planes, out);
    k_mm   <<<dim3(256), dim3(64),  0, stream>>>(planes, sim);
    k_rank <<<dim3(64),  dim3(512), 0, stream>>>(sim, out);
}

// Round 4
// 67.779 us; speedup vs baseline: 1.1246x; 1.0363x over previous
//
#include <hip/hip_runtime.h>

typedef __attribute__((ext_vector_type(8))) short bf16x8;
typedef __attribute__((ext_vector_type(4))) float f32x4;

#define NB 512
#define FD 512
#define PLANE (NB * FD)          // 262144 elements per plane
#define KSPLIT 4
#define KCH (FD / KSPLIT)        // 128 k per slice

// fp32 -> bf16 round-to-nearest-even (bit twiddle; inputs are finite normals)
__device__ __forceinline__ ushort f2bf(float x) {
    uint u = __builtin_bit_cast(uint, x);
    return (ushort)((u + 0x7FFFu + ((u >> 16) & 1u)) >> 16);
}
__device__ __forceinline__ float bf2f(ushort h) {
    uint u = ((uint)h) << 16;
    return __builtin_bit_cast(float, u);
}

// ---------------------------------------------------------------------------
// k_split: fp32 inputs -> 4 bf16 planes in ws: fs_hi | fs_lo | ft_hi | ft_lo.
// 3-term split GEMM (hi*hi + hi*lo + lo*hi) recovers ~fp32 accuracy.
// 512 blocks x 256 threads, one float4 per thread. Also seeds out[0] = 1.0.
// ---------------------------------------------------------------------------
__global__ __launch_bounds__(256)
void k_split(const float* __restrict__ fs, const float* __restrict__ ft,
             ushort* __restrict__ planes, float* __restrict__ out1)
{
    const int t = blockIdx.x * 256 + threadIdx.x;   // 0..131071 float4 chunks
    if (t == 0) out1[0] = 1.0f;                     // k_rank accumulates -ap
    const int mat = t >> 16;                        // 0 = fs, 1 = ft
    const int i4  = t & 65535;                      // float4 index within matrix
    const float4 v = ((const float4*)(mat ? ft : fs))[i4];

    ushort4 hi, lo;
    hi.x = f2bf(v.x); lo.x = f2bf(v.x - bf2f(hi.x));
    hi.y = f2bf(v.y); lo.y = f2bf(v.y - bf2f(hi.y));
    hi.z = f2bf(v.z); lo.z = f2bf(v.z - bf2f(hi.z));
    hi.w = f2bf(v.w); lo.w = f2bf(v.w - bf2f(hi.w));

    ushort4* hp = (ushort4*)(planes + (size_t)mat * 2 * PLANE);
    ushort4* lp = (ushort4*)(planes + (size_t)mat * 2 * PLANE + PLANE);
    hp[i4] = hi;
    lp[i4] = lo;
}

// ---------------------------------------------------------------------------
// k_mm: sim = fs @ ft^T via mfma_f32_16x16x32_bf16, 3-term hi/lo split,
// split-K 4-way. 1024 blocks x 64 threads (1 wave) = 4 waves/CU so L2 load
// latency is hidden by co-resident waves. Each wave: 32x32 tile, K=128 slice,
// NO LDS — fragments load directly from the bf16 planes (16B dwordx4).
// Frag layout (verified m89/m91): A/B lane l = row (l&15), k = 8*(l>>4)+i;
// C/D: col = l&15, row = (l>>4)*4 + reg.
// ---------------------------------------------------------------------------
__global__ __launch_bounds__(64)
void k_mm(const ushort* __restrict__ planes, float* __restrict__ simsl)
{
    const int l    = threadIdx.x;
    const int bid  = blockIdx.x;
    const int ks   = bid >> 8;               // k-slice 0..3
    const int tile = bid & 255;              // 16 x 16 tiles of 32x32
    const int tr   = (tile >> 4) * 32;
    const int tc   = (tile & 15) * 32;
    const int r0   = l & 15;
    const int kg   = ks * KCH + (l >> 4) * 8;   // this lane's k base

    const ushort* fsh = planes;
    const ushort* fsl = planes + PLANE;
    const ushort* fth = planes + 2 * PLANE;
    const ushort* ftl = planes + 3 * PLANE;

    const ushort* pa0h = fsh + (size_t)(tr + r0)      * FD + kg;
    const ushort* pa1h = fsh + (size_t)(tr + r0 + 16) * FD + kg;
    const ushort* pa0l = fsl + (size_t)(tr + r0)      * FD + kg;
    const ushort* pa1l = fsl + (size_t)(tr + r0 + 16) * FD + kg;
    const ushort* pb0h = fth + (size_t)(tc + r0)      * FD + kg;
    const ushort* pb1h = fth + (size_t)(tc + r0 + 16) * FD + kg;
    const ushort* pb0l = ftl + (size_t)(tc + r0)      * FD + kg;
    const ushort* pb1l = ftl + (size_t)(tc + r0 + 16) * FD + kg;

    f32x4 acc[2][2];
    #pragma unroll
    for (int i = 0; i < 2; ++i)
        #pragma unroll
        for (int j = 0; j < 2; ++j) acc[i][j] = (f32x4){0.f, 0.f, 0.f, 0.f};

    #pragma unroll
    for (int k = 0; k < KCH; k += 32) {
        const bf16x8 a0h = *(const bf16x8*)(pa0h + k);
        const bf16x8 a1h = *(const bf16x8*)(pa1h + k);
        const bf16x8 a0l = *(const bf16x8*)(pa0l + k);
        const bf16x8 a1l = *(const bf16x8*)(pa1l + k);
        const bf16x8 b0h = *(const bf16x8*)(pb0h + k);
        const bf16x8 b1h = *(const bf16x8*)(pb1h + k);
        const bf16x8 b0l = *(const bf16x8*)(pb0l + k);
        const bf16x8 b1l = *(const bf16x8*)(pb1l + k);

        acc[0][0] = __builtin_amdgcn_mfma_f32_16x16x32_bf16(a0h, b0h, acc[0][0], 0, 0, 0);
        acc[0][0] = __builtin_amdgcn_mfma_f32_16x16x32_bf16(a0h, b0l, acc[0][0], 0, 0, 0);
        acc[0][0] = __builtin_amdgcn_mfma_f32_16x16x32_bf16(a0l, b0h, acc[0][0], 0, 0, 0);
        acc[0][1] = __builtin_amdgcn_mfma_f32_16x16x32_bf16(a0h, b1h, acc[0][1], 0, 0, 0);
        acc[0][1] = __builtin_amdgcn_mfma_f32_16x16x32_bf16(a0h, b1l, acc[0][1], 0, 0, 0);
        acc[0][1] = __builtin_amdgcn_mfma_f32_16x16x32_bf16(a0l, b1h, acc[0][1], 0, 0, 0);
        acc[1][0] = __builtin_amdgcn_mfma_f32_16x16x32_bf16(a1h, b0h, acc[1][0], 0, 0, 0);
        acc[1][0] = __builtin_amdgcn_mfma_f32_16x16x32_bf16(a1h, b0l, acc[1][0], 0, 0, 0);
        acc[1][0] = __builtin_amdgcn_mfma_f32_16x16x32_bf16(a1l, b0h, acc[1][0], 0, 0, 0);
        acc[1][1] = __builtin_amdgcn_mfma_f32_16x16x32_bf16(a1h, b1h, acc[1][1], 0, 0, 0);
        acc[1][1] = __builtin_amdgcn_mfma_f32_16x16x32_bf16(a1h, b1l, acc[1][1], 0, 0, 0);
        acc[1][1] = __builtin_amdgcn_mfma_f32_16x16x32_bf16(a1l, b1h, acc[1][1], 0, 0, 0);
    }

    // store partial: row = tr + mh*16 + (l>>4)*4 + j, col = tc + nh*16 + r0
    float* dst = simsl + (size_t)ks * NB * NB;
    const int rbase = (l >> 4) * 4;
    #pragma unroll
    for (int mh = 0; mh < 2; ++mh)
        #pragma unroll
        for (int j = 0; j < 4; ++j) {
            const int row = tr + mh * 16 + rbase + j;
            dst[(size_t)row * NB + tc + r0]      = acc[mh][0][j];
            dst[(size_t)row * NB + tc + 16 + r0] = acc[mh][1][j];
        }
}

// ---------------------------------------------------------------------------
// k_rank: sum the 4 K-slices per row, then rank reduction + SmoothAP term.
// 64 blocks (one per identity group) x 512 threads (8 waves, one row each).
// Lane l owns columns 8l..8l+7; lane n==blockIdx holds the in-group sims.
// Block-reduces 8 wave contribs in LDS -> ONE atomic per block (64 total).
// ---------------------------------------------------------------------------
__global__ __launch_bounds__(512)
void k_rank(const float* __restrict__ simsl, float* __restrict__ out1)
{
    __shared__ float part[8];
    const int w = threadIdx.x >> 6;     // wave 0..7 -> row within group
    const int l = threadIdx.x & 63;
    const int n = blockIdx.x;           // identity group (= b>>3)
    const int b = n * 8 + w;

    float r[8];
    #pragma unroll
    for (int q = 0; q < 8; ++q) r[q] = 0.f;
    #pragma unroll
    for (int ks = 0; ks < KSPLIT; ++ks) {
        const float* p = simsl + (size_t)ks * NB * NB + (size_t)b * NB + 8 * l;
        const float4 u = *(const float4*)(p);
        const float4 v = *(const float4*)(p + 4);
        r[0] += u.x; r[1] += u.y; r[2] += u.z; r[3] += u.w;
        r[4] += v.x; r[5] += v.y; r[6] += v.z; r[7] += v.w;
    }

    // s[q] = sim[b, 8n+q]: lane n holds exactly those 8 values
    float s[8];
    #pragma unroll
    for (int q = 0; q < 8; ++q) s[q] = __shfl(r[q], n);

    // per-lane partial rank_all sums over this lane's 8 columns
    float a[8];
    #pragma unroll
    for (int q = 0; q < 8; ++q) a[q] = 0.f;
    #pragma unroll
    for (int q = 0; q < 8; ++q)
        #pragma unroll
        for (int jj = 0; jj < 8; ++jj)
            a[q] += fmaxf(r[jj] - s[q], 0.f);

    // 64-lane butterfly reduce
    #pragma unroll
    for (int off = 1; off < 64; off <<= 1)
        #pragma unroll
        for (int q = 0; q < 8; ++q)
            a[q] += __shfl_xor(a[q], off);

    float contrib = 0.f;
    if (l < 8) {
        float rp = 1.f;
        #pragma unroll
        for (int k = 0; k < 8; ++k) rp += fmaxf(s[k] - s[l], 0.f);
        contrib = rp / (1.f + a[l]);
    }
    contrib += __shfl_xor(contrib, 1);
    contrib += __shfl_xor(contrib, 2);
    contrib += __shfl_xor(contrib, 4);
    if (l == 0) part[w] = contrib;
    __syncthreads();

    if (threadIdx.x == 0) {
        float t = 0.f;
        #pragma unroll
        for (int i = 0; i < 8; ++i) t += part[i];
        atomicAdd(out1, -t * (1.f / (8.f * NB)));
    }
}

// ---------------------------------------------------------------------------
extern "C" void kernel_launch(void* const* d_in, const int* in_sizes, int n_in,
                              void* d_out, int out_size, void* d_ws, size_t ws_size,
                              hipStream_t stream)
{
    const float* fs = (const float*)d_in[0];   // f_s (512x512 f32)
    const float* ft = (const float*)d_in[1];   // f_t (512x512 f32)
    float* out = (float*)d_out;                // scalar f32

    ushort* planes = (ushort*)d_ws;                                         // 2 MB
    float*  simsl  = (float*)((char*)d_ws + 4ull * PLANE * sizeof(ushort)); // 4 MB

    k_split<<<dim3(512),  dim3(256), 0, stream>>>(fs, ft, planes, out);
    k_mm   <<<dim3(1024), dim3(64),  0, stream>>>(planes, simsl);
    k_rank <<<dim3(64),   dim3(512), 0, stream>>>(simsl, out);
}

// Round 5
// 64.345 us; speedup vs baseline: 1.1846x; 1.0534x over previous
//
#include <hip/hip_runtime.h>
#include <hip/hip_bf16.h>

typedef __attribute__((ext_vector_type(8))) short bf16x8;
typedef __attribute__((ext_vector_type(4))) float f32x4;

#define NB 512
#define FD 512
#define KSPLIT 4
#define KCH (FD / KSPLIT)        // 128 k per slice

// ---------------------------------------------------------------------------
// cvt8: 8 consecutive fp32 -> bf16 hi plane + bf16 lo plane (3-term split:
// hi*hi + hi*lo + lo*hi recovers ~fp32 accuracy; verified absmax 0.0 in R3/R4).
// __float2bfloat16 lets the compiler emit packed v_cvt_pk_bf16_f32 (m240).
// ---------------------------------------------------------------------------
__device__ __forceinline__ void cvt8(const float* __restrict__ p,
                                     bf16x8& hi, bf16x8& lo)
{
    const float4 u = *(const float4*)p;
    const float4 v = *(const float4*)(p + 4);
    const float x[8] = {u.x, u.y, u.z, u.w, v.x, v.y, v.z, v.w};
    #pragma unroll
    for (int i = 0; i < 8; ++i) {
        const __hip_bfloat16 h = __float2bfloat16(x[i]);
        hi[i] = __builtin_bit_cast(short, h);
        const float r = x[i] - __bfloat162float(h);
        lo[i] = __builtin_bit_cast(short, __float2bfloat16(r));
    }
}

// ---------------------------------------------------------------------------
// k_mm: sim = fs @ ft^T via mfma_f32_16x16x32_bf16, fused fp32->bf16 hi/lo
// conversion (no separate split pass: 8 fp32 = 16B*2 = same bytes as hi+lo
// bf16 fragments, so VMEM volume is unchanged; conversion is idle-VALU work).
// Split-K 4-way: 1024 blocks x 64 threads (4 waves/CU hide L2 latency, R4-
// verified). Each wave: 32x32 tile, K=128 slice, no LDS.
// Frag layout (verified m89/m91): A/B lane l = row (l&15), k = 8*(l>>4)+i;
// C/D: col = l&15, row = (l>>4)*4 + reg.
// ---------------------------------------------------------------------------
__global__ __launch_bounds__(64)
void k_mm(const float* __restrict__ fs, const float* __restrict__ ft,
          float* __restrict__ simsl, float* __restrict__ out1)
{
    const int l    = threadIdx.x;
    const int bid  = blockIdx.x;
    const int ks   = bid >> 8;               // k-slice 0..3
    const int tile = bid & 255;              // 16 x 16 tiles of 32x32
    const int tr   = (tile >> 4) * 32;
    const int tc   = (tile & 15) * 32;
    const int r0   = l & 15;
    const int kg   = ks * KCH + (l >> 4) * 8;   // this lane's k base

    if (bid == 0 && l == 0) out1[0] = 1.0f;  // k_rank accumulates -ap into this

    const float* pa0 = fs + (size_t)(tr + r0)      * FD + kg;
    const float* pa1 = fs + (size_t)(tr + r0 + 16) * FD + kg;
    const float* pb0 = ft + (size_t)(tc + r0)      * FD + kg;
    const float* pb1 = ft + (size_t)(tc + r0 + 16) * FD + kg;

    f32x4 acc[2][2];
    #pragma unroll
    for (int i = 0; i < 2; ++i)
        #pragma unroll
        for (int j = 0; j < 2; ++j) acc[i][j] = (f32x4){0.f, 0.f, 0.f, 0.f};

    #pragma unroll
    for (int k = 0; k < KCH; k += 32) {
        bf16x8 a0h, a0l, a1h, a1l, b0h, b0l, b1h, b1l;
        cvt8(pa0 + k, a0h, a0l);
        cvt8(pa1 + k, a1h, a1l);
        cvt8(pb0 + k, b0h, b0l);
        cvt8(pb1 + k, b1h, b1l);

        acc[0][0] = __builtin_amdgcn_mfma_f32_16x16x32_bf16(a0h, b0h, acc[0][0], 0, 0, 0);
        acc[0][0] = __builtin_amdgcn_mfma_f32_16x16x32_bf16(a0h, b0l, acc[0][0], 0, 0, 0);
        acc[0][0] = __builtin_amdgcn_mfma_f32_16x16x32_bf16(a0l, b0h, acc[0][0], 0, 0, 0);
        acc[0][1] = __builtin_amdgcn_mfma_f32_16x16x32_bf16(a0h, b1h, acc[0][1], 0, 0, 0);
        acc[0][1] = __builtin_amdgcn_mfma_f32_16x16x32_bf16(a0h, b1l, acc[0][1], 0, 0, 0);
        acc[0][1] = __builtin_amdgcn_mfma_f32_16x16x32_bf16(a0l, b1h, acc[0][1], 0, 0, 0);
        acc[1][0] = __builtin_amdgcn_mfma_f32_16x16x32_bf16(a1h, b0h, acc[1][0], 0, 0, 0);
        acc[1][0] = __builtin_amdgcn_mfma_f32_16x16x32_bf16(a1h, b0l, acc[1][0], 0, 0, 0);
        acc[1][0] = __builtin_amdgcn_mfma_f32_16x16x32_bf16(a1l, b0h, acc[1][0], 0, 0, 0);
        acc[1][1] = __builtin_amdgcn_mfma_f32_16x16x32_bf16(a1h, b1h, acc[1][1], 0, 0, 0);
        acc[1][1] = __builtin_amdgcn_mfma_f32_16x16x32_bf16(a1h, b1l, acc[1][1], 0, 0, 0);
        acc[1][1] = __builtin_amdgcn_mfma_f32_16x16x32_bf16(a1l, b1h, acc[1][1], 0, 0, 0);
    }

    // store partial: row = tr + mh*16 + (l>>4)*4 + j, col = tc + nh*16 + r0
    float* dst = simsl + (size_t)ks * NB * NB;
    const int rbase = (l >> 4) * 4;
    #pragma unroll
    for (int mh = 0; mh < 2; ++mh)
        #pragma unroll
        for (int j = 0; j < 4; ++j) {
            const int row = tr + mh * 16 + rbase + j;
            dst[(size_t)row * NB + tc + r0]      = acc[mh][0][j];
            dst[(size_t)row * NB + tc + 16 + r0] = acc[mh][1][j];
        }
}

// ---------------------------------------------------------------------------
// k_rank: sum the 4 K-slices per row, then rank reduction + SmoothAP term.
// 128 blocks x 256 threads (4 waves, one row per wave; 512 rows total).
// Lane l owns columns 8l..8l+7; lane n (= b>>3) holds the in-group sims.
// Block-reduces 4 wave contribs in LDS -> ONE atomic per block (128 total).
// ---------------------------------------------------------------------------
__global__ __launch_bounds__(256)
void k_rank(const float* __restrict__ simsl, float* __restrict__ out1)
{
    __shared__ float part[4];
    const int w = threadIdx.x >> 6;            // wave 0..3 within block
    const int l = threadIdx.x & 63;
    const int b = blockIdx.x * 4 + w;          // row 0..511
    const int n = b >> 3;                      // identity group

    float r[8];
    #pragma unroll
    for (int q = 0; q < 8; ++q) r[q] = 0.f;
    #pragma unroll
    for (int ks = 0; ks < KSPLIT; ++ks) {
        const float* p = simsl + (size_t)ks * NB * NB + (size_t)b * NB + 8 * l;
        const float4 u = *(const float4*)(p);
        const float4 v = *(const float4*)(p + 4);
        r[0] += u.x; r[1] += u.y; r[2] += u.z; r[3] += u.w;
        r[4] += v.x; r[5] += v.y; r[6] += v.z; r[7] += v.w;
    }

    // s[q] = sim[b, 8n+q]: lane n holds exactly those 8 values
    float s[8];
    #pragma unroll
    for (int q = 0; q < 8; ++q) s[q] = __shfl(r[q], n);

    // per-lane partial rank_all sums over this lane's 8 columns
    float a[8];
    #pragma unroll
    for (int q = 0; q < 8; ++q) a[q] = 0.f;
    #pragma unroll
    for (int q = 0; q < 8; ++q)
        #pragma unroll
        for (int jj = 0; jj < 8; ++jj)
            a[q] += fmaxf(r[jj] - s[q], 0.f);

    // 64-lane butterfly reduce
    #pragma unroll
    for (int off = 1; off < 64; off <<= 1)
        #pragma unroll
        for (int q = 0; q < 8; ++q)
            a[q] += __shfl_xor(a[q], off);

    float contrib = 0.f;
    if (l < 8) {
        float rp = 1.f;
        #pragma unroll
        for (int k = 0; k < 8; ++k) rp += fmaxf(s[k] - s[l], 0.f);
        contrib = rp / (1.f + a[l]);
    }
    contrib += __shfl_xor(contrib, 1);
    contrib += __shfl_xor(contrib, 2);
    contrib += __shfl_xor(contrib, 4);
    if (l == 0) part[w] = contrib;
    __syncthreads();

    if (threadIdx.x == 0) {
        float t = part[0] + part[1] + part[2] + part[3];
        atomicAdd(out1, -t * (1.f / (8.f * NB)));
    }
}

// ---------------------------------------------------------------------------
extern "C" void kernel_launch(void* const* d_in, const int* in_sizes, int n_in,
                              void* d_out, int out_size, void* d_ws, size_t ws_size,
                              hipStream_t stream)
{
    const float* fs = (const float*)d_in[0];   // f_s (512x512 f32)
    const float* ft = (const float*)d_in[1];   // f_t (512x512 f32)
    float* out   = (float*)d_out;              // scalar f32
    float* simsl = (float*)d_ws;               // KSPLIT * 512*512 f32 = 4 MB

    k_mm  <<<dim3(1024), dim3(64),  0, stream>>>(fs, ft, simsl, out);
    k_rank<<<dim3(128),  dim3(256), 0, stream>>>(simsl, out);
}

// Round 6
// 63.075 us; speedup vs baseline: 1.2084x; 1.0201x over previous
//
#include <hip/hip_runtime.h>
#include <hip/hip_bf16.h>

typedef __attribute__((ext_vector_type(8))) short bf16x8;
typedef __attribute__((ext_vector_type(4))) float f32x4;

#define NB 512
#define FD 512

// ---------------------------------------------------------------------------
// cvt8: 8 consecutive fp32 -> bf16 hi plane + bf16 lo plane (3-term split:
// hi*hi + hi*lo + lo*hi recovers ~fp32 accuracy; absmax 0.0 in R3/R4/R5).
// __float2bfloat16 lets the compiler emit packed v_cvt_pk_bf16_f32 (m240).
// ---------------------------------------------------------------------------
__device__ __forceinline__ void cvt8(const float* __restrict__ p,
                                     bf16x8& hi, bf16x8& lo)
{
    const float4 u = *(const float4*)p;
    const float4 v = *(const float4*)(p + 4);
    const float x[8] = {u.x, u.y, u.z, u.w, v.x, v.y, v.z, v.w};
    #pragma unroll
    for (int i = 0; i < 8; ++i) {
        const __hip_bfloat16 h = __float2bfloat16(x[i]);
        hi[i] = __builtin_bit_cast(short, h);
        const float r = x[i] - __bfloat162float(h);
        lo[i] = __builtin_bit_cast(short, __float2bfloat16(r));
    }
}

// ---------------------------------------------------------------------------
// k_mm: sim = fs @ ft^T via mfma_f32_16x16x32_bf16, fused fp32->bf16 hi/lo
// conversion, split-K INSIDE the block: 256 blocks (one 32x32 tile each) x
// 256 threads = 4 waves, wave w owns k-quarter [128w, 128w+128). 1 block/CU
// x 4 waves keeps the R4-verified L2 latency hiding; the K-partials are
// reduced in LDS (12 KB, one barrier) so sim is written exactly once (1 MB,
// no slice round-trip). No LDS in the MFMA loop itself.
// Frag layout (verified m89/m91): A/B lane l = row (l&15), k = 8*(l>>4)+i;
// C/D: col = l&15, row = (l>>4)*4 + reg.
// ---------------------------------------------------------------------------
__global__ __launch_bounds__(256)
void k_mm(const float* __restrict__ fs, const float* __restrict__ ft,
          float* __restrict__ sim, float* __restrict__ out1)
{
    __shared__ f32x4 red[3][64][4];          // waves 1..3 partial accs

    const int tid = threadIdx.x;
    const int l   = tid & 63;
    const int w   = tid >> 6;                // k-quarter 0..3
    const int bid = blockIdx.x;              // 16 x 16 tiles of 32x32
    const int tr  = (bid >> 4) * 32;
    const int tc  = (bid & 15) * 32;
    const int r0  = l & 15;
    const int kg  = w * 128 + (l >> 4) * 8;  // this lane's k base

    if (bid == 0 && tid == 0) out1[0] = 1.0f;   // k_rank accumulates -ap

    const float* pa0 = fs + (size_t)(tr + r0)      * FD + kg;
    const float* pa1 = fs + (size_t)(tr + r0 + 16) * FD + kg;
    const float* pb0 = ft + (size_t)(tc + r0)      * FD + kg;
    const float* pb1 = ft + (size_t)(tc + r0 + 16) * FD + kg;

    f32x4 acc[2][2];
    #pragma unroll
    for (int i = 0; i < 2; ++i)
        #pragma unroll
        for (int j = 0; j < 2; ++j) acc[i][j] = (f32x4){0.f, 0.f, 0.f, 0.f};

    #pragma unroll
    for (int k = 0; k < 128; k += 32) {
        bf16x8 a0h, a0l, a1h, a1l, b0h, b0l, b1h, b1l;
        cvt8(pa0 + k, a0h, a0l);
        cvt8(pa1 + k, a1h, a1l);
        cvt8(pb0 + k, b0h, b0l);
        cvt8(pb1 + k, b1h, b1l);

        acc[0][0] = __builtin_amdgcn_mfma_f32_16x16x32_bf16(a0h, b0h, acc[0][0], 0, 0, 0);
        acc[0][0] = __builtin_amdgcn_mfma_f32_16x16x32_bf16(a0h, b0l, acc[0][0], 0, 0, 0);
        acc[0][0] = __builtin_amdgcn_mfma_f32_16x16x32_bf16(a0l, b0h, acc[0][0], 0, 0, 0);
        acc[0][1] = __builtin_amdgcn_mfma_f32_16x16x32_bf16(a0h, b1h, acc[0][1], 0, 0, 0);
        acc[0][1] = __builtin_amdgcn_mfma_f32_16x16x32_bf16(a0h, b1l, acc[0][1], 0, 0, 0);
        acc[0][1] = __builtin_amdgcn_mfma_f32_16x16x32_bf16(a0l, b1h, acc[0][1], 0, 0, 0);
        acc[1][0] = __builtin_amdgcn_mfma_f32_16x16x32_bf16(a1h, b0h, acc[1][0], 0, 0, 0);
        acc[1][0] = __builtin_amdgcn_mfma_f32_16x16x32_bf16(a1h, b0l, acc[1][0], 0, 0, 0);
        acc[1][0] = __builtin_amdgcn_mfma_f32_16x16x32_bf16(a1l, b0h, acc[1][0], 0, 0, 0);
        acc[1][1] = __builtin_amdgcn_mfma_f32_16x16x32_bf16(a1h, b1h, acc[1][1], 0, 0, 0);
        acc[1][1] = __builtin_amdgcn_mfma_f32_16x16x32_bf16(a1h, b1l, acc[1][1], 0, 0, 0);
        acc[1][1] = __builtin_amdgcn_mfma_f32_16x16x32_bf16(a1l, b1h, acc[1][1], 0, 0, 0);
    }

    // intra-block split-K reduction: waves 1..3 park accs in LDS, wave 0 sums
    if (w != 0) {
        red[w - 1][l][0] = acc[0][0];
        red[w - 1][l][1] = acc[0][1];
        red[w - 1][l][2] = acc[1][0];
        red[w - 1][l][3] = acc[1][1];
    }
    __syncthreads();
    if (w == 0) {
        #pragma unroll
        for (int u = 0; u < 3; ++u) {
            acc[0][0] += red[u][l][0];
            acc[0][1] += red[u][l][1];
            acc[1][0] += red[u][l][2];
            acc[1][1] += red[u][l][3];
        }
        // store: row = tr + mh*16 + (l>>4)*4 + j, col = tc + nh*16 + r0
        const int rbase = (l >> 4) * 4;
        #pragma unroll
        for (int mh = 0; mh < 2; ++mh)
            #pragma unroll
            for (int j = 0; j < 4; ++j) {
                const int row = tr + mh * 16 + rbase + j;
                sim[(size_t)row * NB + tc + r0]      = acc[mh][0][j];
                sim[(size_t)row * NB + tc + 16 + r0] = acc[mh][1][j];
            }
    }
}

// ---------------------------------------------------------------------------
// k_rank: per-row rank reduction + SmoothAP term (single sim slice now).
// 128 blocks x 256 threads (4 waves, one row per wave; 512 rows total).
// Lane l owns columns 8l..8l+7; lane n (= b>>3) holds the in-group sims.
// Block-reduces 4 wave contribs in LDS -> ONE atomic per block (128 total).
// ---------------------------------------------------------------------------
__global__ __launch_bounds__(256)
void k_rank(const float* __restrict__ sim, float* __restrict__ out1)
{
    __shared__ float part[4];
    const int w = threadIdx.x >> 6;            // wave 0..3 within block
    const int l = threadIdx.x & 63;
    const int b = blockIdx.x * 4 + w;          // row 0..511
    const int n = b >> 3;                      // identity group

    const float* p = sim + (size_t)b * NB + 8 * l;
    const float4 u = *(const float4*)(p);
    const float4 v = *(const float4*)(p + 4);
    float r[8] = {u.x, u.y, u.z, u.w, v.x, v.y, v.z, v.w};

    // s[q] = sim[b, 8n+q]: lane n holds exactly those 8 values
    float s[8];
    #pragma unroll
    for (int q = 0; q < 8; ++q) s[q] = __shfl(r[q], n);

    // per-lane partial rank_all sums over this lane's 8 columns
    float a[8];
    #pragma unroll
    for (int q = 0; q < 8; ++q) a[q] = 0.f;
    #pragma unroll
    for (int q = 0; q < 8; ++q)
        #pragma unroll
        for (int jj = 0; jj < 8; ++jj)
            a[q] += fmaxf(r[jj] - s[q], 0.f);

    // 64-lane butterfly reduce
    #pragma unroll
    for (int off = 1; off < 64; off <<= 1)
        #pragma unroll
        for (int q = 0; q < 8; ++q)
            a[q] += __shfl_xor(a[q], off);

    float contrib = 0.f;
    if (l < 8) {
        float rp = 1.f;
        #pragma unroll
        for (int k = 0; k < 8; ++k) rp += fmaxf(s[k] - s[l], 0.f);
        contrib = rp / (1.f + a[l]);
    }
    contrib += __shfl_xor(contrib, 1);
    contrib += __shfl_xor(contrib, 2);
    contrib += __shfl_xor(contrib, 4);
    if (l == 0) part[w] = contrib;
    __syncthreads();

    if (threadIdx.x == 0) {
        float t = part[0] + part[1] + part[2] + part[3];
        atomicAdd(out1, -t * (1.f / (8.f * NB)));
    }
}

// ---------------------------------------------------------------------------
extern "C" void kernel_launch(void* const* d_in, const int* in_sizes, int n_in,
                              void* d_out, int out_size, void* d_ws, size_t ws_size,
                              hipStream_t stream)
{
    const float* fs = (const float*)d_in[0];   // f_s (512x512 f32)
    const float* ft = (const float*)d_in[1];   // f_t (512x512 f32)
    float* out = (float*)d_out;                // scalar f32
    float* sim = (float*)d_ws;                 // 512*512 f32 = 1 MB

    k_mm  <<<dim3(256), dim3(256), 0, stream>>>(fs, ft, sim, out);
    k_rank<<<dim3(128), dim3(256), 0, stream>>>(sim, out);
}